// Round 3
// baseline (507.154 us; speedup 1.0000x reference)
//
#include <hip/hip_runtime.h>
#include <stdint.h>
#include <stddef.h>

typedef float    f32x4 __attribute__((ext_vector_type(4)));
typedef _Float16 f16x4 __attribute__((ext_vector_type(4)));
typedef _Float16 f16x8 __attribute__((ext_vector_type(8)));

#define HH 96
#define MROWS 16
// h1 layout (MFMA-A order): oct = k>>3 (0..31), row (0..15), j = k&7.
// element index = oct*OCTSTRIDE + row*8 + j ; OCTSTRIDE=136 halves (272 B = 68 dw ≡ 4 banks)
#define OCTSTRIDE 136

__launch_bounds__(512, 4)
__global__ void policy_scan_kernel(
    const float* __restrict__ policy,     // (B,96,4)
    const float* __restrict__ noiseT,     // (B,96)
    const float* __restrict__ noiseD,     // (B,96)
    const float* __restrict__ action_pre, // (B,)
    const float* __restrict__ state_pre,  // (B,)
    const float* __restrict__ Lambda1,    // (1,)
    const float* __restrict__ Budget1,    // (1,)
    const float* __restrict__ W1,         // (256,6)
    const float* __restrict__ b1,         // (256,)
    const float* __restrict__ W2,         // (256,256)
    const float* __restrict__ b2,         // (256,)
    const float* __restrict__ W3,         // (256,)
    const float* __restrict__ b3,         // (1,)
    float* __restrict__ out)              // (B,96)
{
    __shared__ __attribute__((aligned(16))) float    featLDS[MROWS*HH*4];   // 24576 B
    __shared__ __attribute__((aligned(16))) float    noiseTLDS[MROWS*HH];   // 6144 B
    __shared__ __attribute__((aligned(16))) float    noiseDLDS[MROWS*HH];   // 6144 B
    __shared__ __attribute__((aligned(16))) _Float16 h1LDS[32*OCTSTRIDE];   // 8704 B
    __shared__ __attribute__((aligned(16))) float    partialLDS[8*17];      // 544 B
    __shared__ float ftT[HH], GamT[HH], invGT[HH];

    const int tid  = threadIdx.x;          // 0..511
    const int wave = tid >> 6;             // 0..7
    const int lane = tid & 63;
    const int l16  = lane & 15;
    const int lq   = lane >> 4;            // 0..3
    const int nq   = lane;                 // neuron-quad id for Phase A (0..63)
    const int r0   = blockIdx.x * MROWS;

    // ---- stage per-block inputs (coalesced; block slice contiguous) ----
    {
        const f32x4* src = (const f32x4*)(policy + (size_t)r0 * HH * 4);
        f32x4* dst = (f32x4*)featLDS;
        #pragma unroll
        for (int i = 0; i < 3; ++i) dst[i*512 + tid] = src[i*512 + tid];
        if (tid < MROWS*HH/4) {
            ((f32x4*)noiseTLDS)[tid] = ((const f32x4*)(noiseT + (size_t)r0 * HH))[tid];
            ((f32x4*)noiseDLDS)[tid] = ((const f32x4*)(noiseD + (size_t)r0 * HH))[tid];
        }
    }
    // ---- per-t constant tables ----
    if (tid < HH) {
        float e  = __builtin_exp2f(-2.0f * (float)(95 - tid));
        float ft = 0.5f * (1.0f - e);
        float G  = 2.0f + ft;
        ftT[tid] = ft; GamT[tid] = G; invGT[tid] = 1.0f / G;
    }

    // ---- W2 -> fp16 B-fragments, register-resident (64 VGPR/lane) ----
    // lane holds n = (wave*2+nt)*16 + l16, k = kc*32 + lq*8 + j
    f16x8 bfr[2][8];
    float b2v[2], w3v[2];
    #pragma unroll
    for (int nt = 0; nt < 2; ++nt) {
        const int n = (wave*2 + nt)*16 + l16;
        const float* wrow = W2 + (size_t)n * 256;
        #pragma unroll
        for (int kc = 0; kc < 8; ++kc) {
            const int k0 = kc*32 + lq*8;
            f32x4 u0 = *(const f32x4*)(wrow + k0);
            f32x4 u1 = *(const f32x4*)(wrow + k0 + 4);
            f16x8 v;
            v[0]=(_Float16)u0[0]; v[1]=(_Float16)u0[1]; v[2]=(_Float16)u0[2]; v[3]=(_Float16)u0[3];
            v[4]=(_Float16)u1[0]; v[5]=(_Float16)u1[1]; v[6]=(_Float16)u1[2]; v[7]=(_Float16)u1[3];
            bfr[nt][kc] = v;
        }
        b2v[nt] = b2[n];
        w3v[nt] = W3[n];
    }

    // ---- W1 for this thread's 4 neurons (4*nq .. 4*nq+3) ----
    float w1r[4][6], b1r[4];
    {
        const int nbase = nq * 4;
        #pragma unroll
        for (int i = 0; i < 4; ++i) {
            #pragma unroll
            for (int j = 0; j < 6; ++j) w1r[i][j] = W1[(nbase+i)*6 + j];
            b1r[i] = b1[nbase + i];
        }
    }

    const float lam  = Lambda1[0];
    const float budH = Budget1[0] / 96.0f;
    const float b3s  = b3[0];
    const float per_step = lam * 2.0f + budH;

    // ---- recurrence state for rows (wave) and (wave+8), replicated across the wave ----
    float stA[2], stS[2], stB[2], stC[2], stSS[2], stAD[2];
    #pragma unroll
    for (int i = 0; i < 2; ++i) {
        const int row = wave + i*8;
        stA[i] = action_pre[r0 + row];
        stS[i] = state_pre[r0 + row];
        stB[i] = per_step;
        stC[i] = 0.0f; stSS[i] = 0.0f; stAD[i] = 0.0f;
    }
    __syncthreads();

    const int h1w = (nq >> 1)*OCTSTRIDE + (nq & 1)*4;   // + row*8
    const int h1r = lq*OCTSTRIDE + l16*8;               // + kc*(4*OCTSTRIDE)

    float dem[2];

    #pragma unroll 1
    for (int t = 0; t < HH; ++t) {
        // ---- Phase A: layer 1 (fp32), write h1 (fp16) in MFMA-A layout ----
        #pragma unroll
        for (int i = 0; i < 2; ++i) {
            const int row = wave + i*8;
            f32x4 f = *(const f32x4*)&featLDS[(row*HH + t)*4];   // broadcast
            dem[i] = f[0];
            f16x4 hv;
            #pragma unroll
            for (int j = 0; j < 4; ++j) {
                float h = b1r[j];
                h = fmaf(w1r[j][0], f[0], h); h = fmaf(w1r[j][1], f[1], h);
                h = fmaf(w1r[j][2], f[2], h); h = fmaf(w1r[j][3], f[3], h);
                h = fmaf(w1r[j][4], stA[i], h); h = fmaf(w1r[j][5], stS[i], h);
                hv[j] = (_Float16)fmaxf(h, 0.0f);
            }
            *(f16x4*)&h1LDS[h1w + row*8] = hv;   // ds_write_b64, 2-way (free)
        }
        __syncthreads();   // bar1: h1 ready

        // ---- Phase B: layer 2 MFMA (fp16, single pass); A-frag shared by both n-tiles ----
        f32x4 acc0 = {0.f,0.f,0.f,0.f}, acc1 = {0.f,0.f,0.f,0.f};
        #pragma unroll
        for (int kc = 0; kc < 8; ++kc) {
            f16x8 a = *(const f16x8*)&h1LDS[h1r + kc*(4*OCTSTRIDE)];  // contiguous per 16-lane phase
            acc0 = __builtin_amdgcn_mfma_f32_16x16x32_f16(a, bfr[0][kc], acc0, 0, 0, 0);
            acc1 = __builtin_amdgcn_mfma_f32_16x16x32_f16(a, bfr[1][kc], acc1, 0, 0, 0);
        }

        // ---- Phase C: bias+relu, dot W3, reduce over l16 ----
        // acc[r] = h2pre[m=lq*4+r][n-tile col l16]
        f32x4 p;
        #pragma unroll
        for (int r = 0; r < 4; ++r) {
            float v = w3v[0] * fmaxf(acc0[r] + b2v[0], 0.0f);
            v = fmaf(w3v[1], fmaxf(acc1[r] + b2v[1], 0.0f), v);
            p[r] = v;
        }
        #pragma unroll
        for (int m = 1; m < 16; m <<= 1) {
            p[0] += __shfl_xor(p[0], m);
            p[1] += __shfl_xor(p[1], m);
            p[2] += __shfl_xor(p[2], m);
            p[3] += __shfl_xor(p[3], m);
        }
        if (l16 == 0) {
            #pragma unroll
            for (int r = 0; r < 4; ++r) partialLDS[wave*17 + lq*4 + r] = p[r];
        }
        __syncthreads();   // bar2: partials ready

        // ---- Phase D: recurrence, replicated across the wave (rows wave, wave+8) ----
        const float ft = ftT[t], Gam = GamT[t], invG = invGT[t];
        #pragma unroll
        for (int i = 0; i < 2; ++i) {
            const int row = wave + i*8;
            float psum = 0.0f;
            #pragma unroll
            for (int w = 0; w < 8; ++w) psum += partialLDS[w*17 + row];  // broadcast
            float a_ml   = fmaxf(psum + b3s, 0.0f);
            float nT     = noiseTLDS[row*HH + t];
            float nD     = noiseDLDS[row*HH + t];
            float a_prior = fminf(fmaxf(stS[i] + dem[i], 0.0f) * 1.25f, 10.0f);
            float sgn    = (a_ml < a_prior) ? 1.0f : -1.0f;
            float a_out  = fmaf(fmaxf(fabsf(a_ml - a_prior) - stB[i] * invG, 0.0f), sgn, a_ml);
            float ns     = fminf(fmaxf(stS[i] * (1.0f - nD) + dem[i] - (0.8f + nT) * a_out, 0.0f), 15.0f);
            float c_cost = fmaf(fmaf(0.1f, ns, 1.0f), ns, 2.0f);
            float ad_new = fabsf(a_out - a_prior);
            float cum_dv = fmaf(2.0f, ad_new, 0.375f * stSS[i]);
            float c_prior = fmaxf(2.0f, c_cost - cum_dv);
            float cum_c_new = stC[i] + (1.0f + lam) * c_prior - c_cost;
            float T      = fmaf(0.25f, stSS[i], ad_new);
            float cum_dg = ft * T;
            float bgt_if = fmaxf(fmaxf(stB[i] + per_step - ad_new * Gam, 0.0f),
                                 cum_c_new - cum_dg + lam * 2.0f + budH * ((float)t + 2.0f));
            float bgt_else = fmaxf(stB[i] + per_step - stAD[i] * Gam, 0.0f);
            if (t == HH - 1) { stB[i] = bgt_else; }
            else             { stB[i] = bgt_if; stC[i] = cum_c_new; }
            stSS[i] = T;
            stAD[i] = ad_new;
            stA[i]  = a_out;
            stS[i]  = ns;
            if (nq == 0) out[(size_t)(r0 + row) * HH + t] = a_out;
        }
        // no barrier here: D(t)+A(t+1) both precede bar1(t+1); h1 reads finished before bar2(t)
    }
}

extern "C" void kernel_launch(void* const* d_in, const int* in_sizes, int n_in,
                              void* d_out, int out_size, void* d_ws, size_t ws_size,
                              hipStream_t stream) {
    policy_scan_kernel<<<dim3(8192 / MROWS), dim3(512), 0, stream>>>(
        (const float*)d_in[0],  // policy_in_c
        (const float*)d_in[1],  // trans_noise
        (const float*)d_in[2],  // demand_noise
        (const float*)d_in[3],  // action_pre
        (const float*)d_in[4],  // state_pre
        (const float*)d_in[5],  // Lambda
        (const float*)d_in[6],  // Budget
        (const float*)d_in[7],  // W1
        (const float*)d_in[8],  // b1
        (const float*)d_in[9],  // W2
        (const float*)d_in[10], // b2
        (const float*)d_in[11], // W3
        (const float*)d_in[12], // b3
        (float*)d_out);
}

// Round 4
// 292.435 us; speedup vs baseline: 1.7342x; 1.7342x over previous
//
#include <hip/hip_runtime.h>
#include <stdint.h>
#include <stddef.h>

typedef float    f32x4 __attribute__((ext_vector_type(4)));
typedef _Float16 f16x8 __attribute__((ext_vector_type(8)));

#define HH 96
#define MROWS 16
// h1 in MFMA-A-fragment order: element = (k>>3)*OCT + m*8 + (k&7), fp16
// OCT=136 halves (272 B): b128 reads 16B-aligned, oct-to-oct bank step 4
#define OCT 136

__launch_bounds__(512, 4)
__global__ void policy_scan_kernel(
    const float* __restrict__ policy,     // (B,96,4)
    const float* __restrict__ noiseT,     // (B,96)
    const float* __restrict__ noiseD,     // (B,96)
    const float* __restrict__ action_pre, // (B,)
    const float* __restrict__ state_pre,  // (B,)
    const float* __restrict__ Lambda1,    // (1,)
    const float* __restrict__ Budget1,    // (1,)
    const float* __restrict__ W1,         // (256,6)
    const float* __restrict__ b1,         // (256,)
    const float* __restrict__ W2,         // (256,256)
    const float* __restrict__ b2,         // (256,)
    const float* __restrict__ W3,         // (256,)
    const float* __restrict__ b3,         // (1,)
    float* __restrict__ out)              // (B,96)
{
    __shared__ __attribute__((aligned(16))) float    featLDS[HH*MROWS*4];  // [t][row][c] 24576 B
    __shared__ __attribute__((aligned(16))) float    noiseTLDS[HH*MROWS];  // [t][row] 6144 B
    __shared__ __attribute__((aligned(16))) float    noiseDLDS[HH*MROWS];  // 6144 B
    __shared__ __attribute__((aligned(16))) _Float16 h1LDS[32*OCT];        // 8704 B
    __shared__ __attribute__((aligned(16))) float    partialLDS[8*20];     // 640 B
    __shared__ float ftT[HH], GamT[HH], invGT[HH];

    const int tid  = threadIdx.x;          // 0..511
    const int wave = tid >> 6;             // 0..7
    const int lane = tid & 63;
    const int l16  = lane & 15;
    const int lq   = lane >> 4;            // 0..3
    const int r0   = blockIdx.x * MROWS;

    // ---- stage inputs, transposed to [t][row] for conflict-free per-lane-row reads ----
    {
        const f32x4* src = (const f32x4*)(policy + (size_t)r0 * HH * 4);
        #pragma unroll
        for (int i = 0; i < 3; ++i) {
            int idx = i*512 + tid;             // idx = row*96 + t
            int row = idx / 96, t = idx - row*96;
            *(f32x4*)&featLDS[(t*MROWS + row)*4] = src[idx];
        }
        if (tid < 384) {
            int row = tid / 24, tq = tid - row*24;
            f32x4 v1 = *(const f32x4*)(noiseT + (size_t)r0*HH + row*HH + tq*4);
            f32x4 v2 = *(const f32x4*)(noiseD + (size_t)r0*HH + row*HH + tq*4);
            #pragma unroll
            for (int j = 0; j < 4; ++j) {
                noiseTLDS[(tq*4+j)*MROWS + row] = v1[j];
                noiseDLDS[(tq*4+j)*MROWS + row] = v2[j];
            }
        }
        if (tid < HH) {
            float e  = __builtin_exp2f(-2.0f * (float)(95 - tid));
            float ft = 0.5f * (1.0f - e);
            ftT[tid] = ft; GamT[tid] = 2.0f + ft; invGT[tid] = 1.0f / (2.0f + ft);
        }
    }

    // ---- W2 -> fp16 B-frags (64 VGPR), W1 -> fp16 B-frags (8 VGPR), biases ----
    // lane holds n = (wave*2+nt)*16 + l16; k = lq*8+j (layer1), kc*32+lq*8+j (layer2)
    f16x8 bfr[2][8], w1fr[2];
    float b2v[2], w3v[2], b1v[2];
    int   h1w[2];
    #pragma unroll
    for (int nt = 0; nt < 2; ++nt) {
        const int n = (wave*2 + nt)*16 + l16;
        const float* wrow = W2 + (size_t)n * 256;
        #pragma unroll
        for (int kc = 0; kc < 8; ++kc) {
            const int k0 = kc*32 + lq*8;
            f32x4 u0 = *(const f32x4*)(wrow + k0);
            f32x4 u1 = *(const f32x4*)(wrow + k0 + 4);
            f16x8 v;
            v[0]=(_Float16)u0[0]; v[1]=(_Float16)u0[1]; v[2]=(_Float16)u0[2]; v[3]=(_Float16)u0[3];
            v[4]=(_Float16)u1[0]; v[5]=(_Float16)u1[1]; v[6]=(_Float16)u1[2]; v[7]=(_Float16)u1[3];
            bfr[nt][kc] = v;
        }
        b2v[nt] = b2[n]; w3v[nt] = W3[n]; b1v[nt] = b1[n];
        f16x8 w = {};
        if (lq == 0) {
            #pragma unroll
            for (int j = 0; j < 6; ++j) w[j] = (_Float16)W1[n*6 + j];
        }
        w1fr[nt] = w;
        h1w[nt] = (n >> 3)*OCT + (n & 7);      // + m*8
    }
    const int h1r = lq*OCT + l16*8;            // + kc*(4*OCT)

    const float lam  = Lambda1[0];
    const float budH = Budget1[0] / 96.0f;
    const float b3s  = b3[0];
    const float per_step = lam * 2.0f + budH;

    // ---- recurrence state: lane owns row l16 (replicated across lq and waves) ----
    float stA = action_pre[r0 + l16];
    float stS = state_pre[r0 + l16];
    float stB = per_step, stC = 0.0f, stSS = 0.0f, stAD = 0.0f;
    __syncthreads();

    #pragma unroll 1
    for (int t = 0; t < HH; ++t) {
        // ---- Phase A: layer 1 via MFMA (K=6 zero-padded to 32) ----
        f32x4 f = *(const f32x4*)&featLDS[(t*MROWS + l16)*4];   // 2-way, free
        float dem = f[0];
        f16x8 xf = {};
        if (lq == 0) {
            xf[0]=(_Float16)f[0]; xf[1]=(_Float16)f[1];
            xf[2]=(_Float16)f[2]; xf[3]=(_Float16)f[3];
            xf[4]=(_Float16)stA;  xf[5]=(_Float16)stS;
        }
        f32x4 g0 = {0.f,0.f,0.f,0.f}, g1 = {0.f,0.f,0.f,0.f};
        g0 = __builtin_amdgcn_mfma_f32_16x16x32_f16(xf, w1fr[0], g0, 0, 0, 0);
        g1 = __builtin_amdgcn_mfma_f32_16x16x32_f16(xf, w1fr[1], g1, 0, 0, 0);
        // g[nt][r] = h1pre[m=lq*4+r][n]; bias+relu, write fp16 in A-layout
        #pragma unroll
        for (int r = 0; r < 4; ++r) {
            h1LDS[h1w[0] + (lq*4+r)*8] = (_Float16)fmaxf(g0[r] + b1v[0], 0.0f);
            h1LDS[h1w[1] + (lq*4+r)*8] = (_Float16)fmaxf(g1[r] + b1v[1], 0.0f);
        }
        __syncthreads();   // bar1: h1 complete

        // ---- Phase B: layer 2 MFMA; A-frag shared by both n-tiles ----
        f32x4 acc0 = {0.f,0.f,0.f,0.f}, acc1 = {0.f,0.f,0.f,0.f};
        #pragma unroll
        for (int kc = 0; kc < 8; ++kc) {
            f16x8 a = *(const f16x8*)&h1LDS[h1r + kc*(4*OCT)];
            acc0 = __builtin_amdgcn_mfma_f32_16x16x32_f16(a, bfr[0][kc], acc0, 0, 0, 0);
            acc1 = __builtin_amdgcn_mfma_f32_16x16x32_f16(a, bfr[1][kc], acc1, 0, 0, 0);
        }

        // ---- Phase C: bias+relu, dot W3, reduce over the 16 n-cols of each tile ----
        f32x4 p;
        #pragma unroll
        for (int r = 0; r < 4; ++r) {
            float v = w3v[0] * fmaxf(acc0[r] + b2v[0], 0.0f);
            v = fmaf(w3v[1], fmaxf(acc1[r] + b2v[1], 0.0f), v);
            p[r] = v;
        }
        #pragma unroll
        for (int m = 1; m < 16; m <<= 1) {
            p[0] += __shfl_xor(p[0], m);
            p[1] += __shfl_xor(p[1], m);
            p[2] += __shfl_xor(p[2], m);
            p[3] += __shfl_xor(p[3], m);
        }
        if (l16 == 0) *(f32x4*)&partialLDS[wave*20 + lq*4] = p;  // row m=lq*4+r
        __syncthreads();   // bar2: partials complete

        // ---- Phase D: recurrence for row l16 (replicated across lq/wave) ----
        float psum = 0.0f;
        #pragma unroll
        for (int w = 0; w < 8; ++w) psum += partialLDS[w*20 + l16];  // broadcast
        const float ft = ftT[t], Gam = GamT[t], invG = invGT[t];
        float a_ml   = fmaxf(psum + b3s, 0.0f);
        float nT     = noiseTLDS[t*MROWS + l16];
        float nD     = noiseDLDS[t*MROWS + l16];
        float a_prior = fminf(fmaxf(stS + dem, 0.0f) * 1.25f, 10.0f);
        float sgn    = (a_ml < a_prior) ? 1.0f : -1.0f;
        float a_out  = fmaf(fmaxf(fabsf(a_ml - a_prior) - stB * invG, 0.0f), sgn, a_ml);
        float ns     = fminf(fmaxf(stS * (1.0f - nD) + dem - (0.8f + nT) * a_out, 0.0f), 15.0f);
        float c_cost = fmaf(fmaf(0.1f, ns, 1.0f), ns, 2.0f);
        float ad_new = fabsf(a_out - a_prior);
        float cum_dv = fmaf(2.0f, ad_new, 0.375f * stSS);
        float c_prior = fmaxf(2.0f, c_cost - cum_dv);
        float cum_c_new = stC + (1.0f + lam) * c_prior - c_cost;
        float T      = fmaf(0.25f, stSS, ad_new);
        float cum_dg = ft * T;
        float bgt_if = fmaxf(fmaxf(stB + per_step - ad_new * Gam, 0.0f),
                             cum_c_new - cum_dg + lam * 2.0f + budH * ((float)t + 2.0f));
        float bgt_else = fmaxf(stB + per_step - stAD * Gam, 0.0f);
        if (t == HH - 1) { stB = bgt_else; }
        else             { stB = bgt_if; stC = cum_c_new; }
        stSS = T;
        stAD = ad_new;
        stA  = a_out;
        stS  = ns;
        if (tid < MROWS) out[(size_t)(r0 + tid) * HH + t] = a_out;
        // no barrier: D reads (bar2-protected) done in-wave; A(t+1) h1 writes are
        // safe because all h1 reads completed before bar2(t).
    }
}

extern "C" void kernel_launch(void* const* d_in, const int* in_sizes, int n_in,
                              void* d_out, int out_size, void* d_ws, size_t ws_size,
                              hipStream_t stream) {
    policy_scan_kernel<<<dim3(8192 / MROWS), dim3(512), 0, stream>>>(
        (const float*)d_in[0],  // policy_in_c
        (const float*)d_in[1],  // trans_noise
        (const float*)d_in[2],  // demand_noise
        (const float*)d_in[3],  // action_pre
        (const float*)d_in[4],  // state_pre
        (const float*)d_in[5],  // Lambda
        (const float*)d_in[6],  // Budget
        (const float*)d_in[7],  // W1
        (const float*)d_in[8],  // b1
        (const float*)d_in[9],  // W2
        (const float*)d_in[10], // b2
        (const float*)d_in[11], // W3
        (const float*)d_in[12], // b3
        (float*)d_out);
}

// Round 5
// 224.314 us; speedup vs baseline: 2.2609x; 1.3037x over previous
//
#include <hip/hip_runtime.h>
#include <stdint.h>
#include <stddef.h>

typedef float    f32x4 __attribute__((ext_vector_type(4)));
typedef float    f32x2 __attribute__((ext_vector_type(2)));
typedef _Float16 f16x4 __attribute__((ext_vector_type(4)));
typedef _Float16 f16x8 __attribute__((ext_vector_type(8)));

#define HH 96
#define MROWS 16
#define OCT 136      // h1 A-layout oct stride in halves (272 B)
#define NSTR 32      // noiseTD per-t stride in dwords (16 rows x float2)
#define OSTR 100     // outLDS row stride in dwords

// 16-lane-row sum via DPP (VALU, no DS): xor1, xor2 (quad_perm), ror4, ror8
#define DPP_ADD(v, ctrl) \
    ((v) + __builtin_bit_cast(float, __builtin_amdgcn_update_dpp( \
        0, __builtin_bit_cast(int, (v)), (ctrl), 0xF, 0xF, true)))

__launch_bounds__(256, 2)
__global__ void policy_scan_kernel(
    const float* __restrict__ policy,     // (B,96,4)
    const float* __restrict__ noiseT,     // (B,96)
    const float* __restrict__ noiseD,     // (B,96)
    const float* __restrict__ action_pre, // (B,)
    const float* __restrict__ state_pre,  // (B,)
    const float* __restrict__ Lambda1,    // (1,)
    const float* __restrict__ Budget1,    // (1,)
    const float* __restrict__ W1,         // (256,6)
    const float* __restrict__ b1,         // (256,)
    const float* __restrict__ W2,         // (256,256)
    const float* __restrict__ b2,         // (256,)
    const float* __restrict__ W3,         // (256,)
    const float* __restrict__ b3,         // (1,)
    float* __restrict__ out)              // (B,96)
{
    __shared__ __attribute__((aligned(16))) float    featLDS[HH*MROWS*4];  // [t][row][4] 24576 B
    __shared__ __attribute__((aligned(16))) float    noiseTD[HH*NSTR];     // [t][row][2] 12288 B
    __shared__ __attribute__((aligned(16))) _Float16 h1LDS[32*OCT];        // 8704 B
    __shared__ __attribute__((aligned(16))) float    partialLDS[MROWS*4];  // [m][w] 256 B
    __shared__ __attribute__((aligned(16))) float    tblLDS[HH*4];         // [t]{ft,Gam,invG,bcoef}
    __shared__ __attribute__((aligned(16))) float    outLDS[MROWS*OSTR];   // 6400 B

    const int tid  = threadIdx.x;          // 0..255
    const int wave = tid >> 6;             // 0..3
    const int lane = tid & 63;
    const int l16  = lane & 15;
    const int lq   = lane >> 4;            // 0..3
    const int r0   = blockIdx.x * MROWS;

    // ---- stage inputs ----
    {
        const f32x4* src = (const f32x4*)(policy + (size_t)r0 * HH * 4);
        #pragma unroll
        for (int i = 0; i < 6; ++i) {
            int idx = i*256 + tid;                 // idx = row*96 + t
            int row = idx / 96, t = idx - row*96;
            *(f32x4*)&featLDS[(t*MROWS + row)*4] = src[idx];
        }
        const float* s1 = noiseT + (size_t)r0 * HH;
        const float* s2 = noiseD + (size_t)r0 * HH;
        #pragma unroll
        for (int i = 0; i < 6; ++i) {
            int idx = i*256 + tid;
            int row = idx / 96, t = idx - row*96;
            noiseTD[t*NSTR + row*2    ] = s1[idx];
            noiseTD[t*NSTR + row*2 + 1] = s2[idx];
        }
    }
    const float lam  = Lambda1[0];
    const float budH = Budget1[0] * (1.0f/96.0f);
    const float b3s  = b3[0];
    const float per_step = lam * 2.0f + budH;
    if (tid < HH) {
        float e  = __builtin_exp2f(-2.0f * (float)(95 - tid));
        float ft = 0.5f * (1.0f - e);
        float G  = 2.0f + ft;
        *(f32x4*)&tblLDS[tid*4] = f32x4{ft, G, 1.0f/G, lam*2.0f + budH*((float)tid + 2.0f)};
    }

    // ---- W2 -> fp16 B-frags: 4 n-tiles/wave (128 VGPR) ----
    // tile tt covers n = wave*64 + tt*16 + l16 ; k = kc*32 + lq*8 + j
    f16x8 bfr[4][8];
    float b2v[4], w3v[4];
    #pragma unroll
    for (int tt = 0; tt < 4; ++tt) {
        const int n = wave*64 + tt*16 + l16;
        const float* wrow = W2 + (size_t)n * 256;
        #pragma unroll
        for (int kc = 0; kc < 8; ++kc) {
            const int k0 = kc*32 + lq*8;
            f32x4 u0 = *(const f32x4*)(wrow + k0);
            f32x4 u1 = *(const f32x4*)(wrow + k0 + 4);
            f16x8 v;
            v[0]=(_Float16)u0[0]; v[1]=(_Float16)u0[1]; v[2]=(_Float16)u0[2]; v[3]=(_Float16)u0[3];
            v[4]=(_Float16)u1[0]; v[5]=(_Float16)u1[1]; v[6]=(_Float16)u1[2]; v[7]=(_Float16)u1[3];
            bfr[tt][kc] = v;
        }
        b2v[tt] = b2[n];
        w3v[tt] = W3[n];
    }

    // ---- W1 as MFMA A-frags for h1^T = W1.x^T (bias folded at k=6) ----
    f16x8 w1A[4];
    #pragma unroll
    for (int tt = 0; tt < 4; ++tt) {
        f16x8 w = {};
        if (lq == 0) {
            const int nn = wave*64 + tt*16 + l16;   // A row m' = l16 -> neuron
            #pragma unroll
            for (int j = 0; j < 6; ++j) w[j] = (_Float16)W1[nn*6 + j];
            w[6] = (_Float16)b1[nn];
        }
        w1A[tt] = w;
    }

    // h1 write: value (tt,r) -> k = wave*64+tt*16+lq*4+r, m = l16
    // addr(halves) = (k>>3)*OCT + m*8 + (k&7); r=0..3 contiguous -> b64
    const int h1wbase = (wave*8 + (lq>>1))*OCT + l16*8 + (lq&1)*4;
    const int h1r     = lq*OCT + l16*8;          // + kc*(4*OCT)

    // ---- recurrence state: lane owns row l16 (replicated across lq/wave) ----
    float stA = action_pre[r0 + l16];
    float stS = state_pre[r0 + l16];
    float stB = per_step, stC = 0.0f, stSS = 0.0f, stAD = 0.0f;
    __syncthreads();

    #pragma unroll 1
    for (int t = 0; t < HH; ++t) {
        // ---- Phase A: layer 1 via MFMA, h1^T orientation ----
        f32x4 f = *(const f32x4*)&featLDS[(t*MROWS + l16)*4];
        float dem = f[0];
        f16x8 xB = {};
        if (lq == 0) {
            xB[0]=(_Float16)f[0]; xB[1]=(_Float16)f[1];
            xB[2]=(_Float16)f[2]; xB[3]=(_Float16)f[3];
            xB[4]=(_Float16)stA;  xB[5]=(_Float16)stS;
            xB[6]=(_Float16)1.0f;
        }
        #pragma unroll
        for (int tt = 0; tt < 4; ++tt) {
            f32x4 g = {0.f,0.f,0.f,0.f};
            g = __builtin_amdgcn_mfma_f32_16x16x32_f16(w1A[tt], xB, g, 0, 0, 0);
            f16x4 hv;
            #pragma unroll
            for (int r = 0; r < 4; ++r) hv[r] = (_Float16)fmaxf(g[r], 0.0f);
            *(f16x4*)&h1LDS[h1wbase + tt*(2*OCT)] = hv;    // ds_write_b64
        }
        __syncthreads();   // bar1: h1 complete

        // ---- Phase B: layer 2, A-frag shared across 4 n-tiles ----
        f32x4 acc[4];
        #pragma unroll
        for (int tt = 0; tt < 4; ++tt) acc[tt] = f32x4{0.f,0.f,0.f,0.f};
        #pragma unroll
        for (int kc = 0; kc < 8; ++kc) {
            f16x8 a = *(const f16x8*)&h1LDS[h1r + kc*(4*OCT)];
            #pragma unroll
            for (int tt = 0; tt < 4; ++tt)
                acc[tt] = __builtin_amdgcn_mfma_f32_16x16x32_f16(a, bfr[tt][kc], acc[tt], 0, 0, 0);
        }

        // ---- Phase C: bias+relu, dot W3; 16-lane reduce via DPP (VALU only) ----
        #pragma unroll
        for (int r = 0; r < 4; ++r) {
            float v = 0.f;
            #pragma unroll
            for (int tt = 0; tt < 4; ++tt)
                v = fmaf(w3v[tt], fmaxf(acc[tt][r] + b2v[tt], 0.0f), v);
            v = DPP_ADD(v, 0xB1);    // quad_perm [1,0,3,2]  (xor 1)
            v = DPP_ADD(v, 0x4E);    // quad_perm [2,3,0,1]  (xor 2)
            v = DPP_ADD(v, 0x124);   // row_ror:4
            v = DPP_ADD(v, 0x128);   // row_ror:8 -> full row sum in all lanes
            if (l16 == 0) partialLDS[(lq*4 + r)*4 + wave] = v;   // [m][w]
        }
        __syncthreads();   // bar2: partials complete

        // ---- Phase D: recurrence for row l16 (replicated) ----
        f32x4 q  = *(const f32x4*)&partialLDS[l16*4];            // w=0..3
        f32x4 tb = *(const f32x4*)&tblLDS[t*4];                  // wave-uniform
        f32x2 nz = *(const f32x2*)&noiseTD[t*NSTR + l16*2];
        float psum = (q[0] + q[1]) + (q[2] + q[3]);
        float a_ml   = fmaxf(psum + b3s, 0.0f);
        float a_prior = fminf(fmaxf(stS + dem, 0.0f) * 1.25f, 10.0f);
        float sgn    = (a_ml < a_prior) ? 1.0f : -1.0f;
        float a_out  = fmaf(fmaxf(fabsf(a_ml - a_prior) - stB * tb[2], 0.0f), sgn, a_ml);
        float ns     = fminf(fmaxf(stS * (1.0f - nz[1]) + dem - (0.8f + nz[0]) * a_out, 0.0f), 15.0f);
        float c_cost = fmaf(fmaf(0.1f, ns, 1.0f), ns, 2.0f);
        float ad_new = fabsf(a_out - a_prior);
        float cum_dv = fmaf(2.0f, ad_new, 0.375f * stSS);
        float c_prior = fmaxf(2.0f, c_cost - cum_dv);
        float cum_c_new = stC + (1.0f + lam) * c_prior - c_cost;
        float T      = fmaf(0.25f, stSS, ad_new);
        float cum_dg = tb[0] * T;
        float bgt_if = fmaxf(fmaxf(stB + per_step - ad_new * tb[1], 0.0f),
                             cum_c_new - cum_dg + tb[3]);
        float bgt_else = fmaxf(stB + per_step - stAD * tb[1], 0.0f);
        if (t == HH - 1) { stB = bgt_else; }
        else             { stB = bgt_if; stC = cum_c_new; }
        stSS = T;
        stAD = ad_new;
        stA  = a_out;
        stS  = ns;
        if (tid < MROWS) outLDS[tid*OSTR + t] = a_out;
        // no barrier: D's reads are bar2-protected; A(t+1) writes race-free (see r4 proof)
    }

    // ---- coalesced output dump ----
    __syncthreads();
    float* oslice = out + (size_t)r0 * HH;
    #pragma unroll
    for (int i = 0; i < 3; ++i) {
        int idx = (i*256 + tid) * 2;               // 1536 dwords total
        int row = idx / 96, c = idx - row*96;      // pairs never straddle rows (96 even)
        f32x2 v = { outLDS[row*OSTR + c], outLDS[row*OSTR + c + 1] };
        *(f32x2*)&oslice[idx] = v;
    }
}

extern "C" void kernel_launch(void* const* d_in, const int* in_sizes, int n_in,
                              void* d_out, int out_size, void* d_ws, size_t ws_size,
                              hipStream_t stream) {
    policy_scan_kernel<<<dim3(8192 / MROWS), dim3(256), 0, stream>>>(
        (const float*)d_in[0],  // policy_in_c
        (const float*)d_in[1],  // trans_noise
        (const float*)d_in[2],  // demand_noise
        (const float*)d_in[3],  // action_pre
        (const float*)d_in[4],  // state_pre
        (const float*)d_in[5],  // Lambda
        (const float*)d_in[6],  // Budget
        (const float*)d_in[7],  // W1
        (const float*)d_in[8],  // b1
        (const float*)d_in[9],  // W2
        (const float*)d_in[10], // b2
        (const float*)d_in[11], // W3
        (const float*)d_in[12], // b3
        (float*)d_out);
}